// Round 6
// baseline (377.815 us; speedup 1.0000x reference)
//
#include <hip/hip_runtime.h>

// Problem constants (from reference setup_inputs)
#define L_DIM 12
#define B_DIM 8
#define H_DIM 12
#define S2    147456              // 384*384
#define M_DIM 32
#define NL 3
#define NH 4
#define HS2   (H_DIM * S2)        // batch stride in attn elements

// design
#define C      128                // st elements per block (chunk)
#define NCH    (S2 / C)           // 1152 blocks
#define NSLOT  8                  // pair-slots in stage pool (8 KB each)
#define DEPTH  6                  // prefetch depth in pair-steps
#define PMSTRIDE 1026             // floats per m-row of pm (8*128 + 2 pad)

#define PART_FLOATS (NCH * 256)
#define META_INTS   1536
// mi layout: [0]=np ; [8..168) plane base offsets (padded, clamped) ;
//            [168..168+1176) weight bytes packed 4 m/int, 8 ints/plane (zero padded)

typedef const __attribute__((address_space(1))) void GAS;
typedef __attribute__((address_space(3))) void LAS;

// ---------------- setup: parallel, LDS-only ----------------
__global__ __launch_bounds__(256) void pfe_setup(
    const int* __restrict__ lidx, const int* __restrict__ hidx, int* __restrict__ mi)
{
    __shared__ unsigned char s_cl[M_DIM][16];
    __shared__ unsigned char s_ch[M_DIM][16];
    __shared__ int s_used[144];
    __shared__ int s_slot[144];
    const int t = threadIdx.x;
    for (int i = t; i < 1176; i += 256) mi[168 + i] = 0;   // zero weight region
    if (t < M_DIM) {
        for (int l = 0; l < L_DIM; ++l) s_cl[t][l] = 0;
        for (int h = 0; h < H_DIM; ++h) s_ch[t][h] = 0;
        for (int i = 0; i < NL; ++i) s_cl[t][lidx[t * NL + i]]++;
        for (int j = 0; j < NH; ++j) s_ch[t][hidx[t * NH + j]]++;
    }
    __syncthreads();
    if (t < 144) {
        const int l = t / H_DIM, h = t % H_DIM;
        int u = 0;
        for (int m = 0; m < M_DIM; ++m) u |= (s_cl[m][l] && s_ch[m][h]) ? 1 : 0;
        s_used[t] = u;
    }
    __syncthreads();
    if (t == 0) {
        int np = 0, lastb = 0;
        for (int k = 0; k < 144; ++k) {
            if (s_used[k]) {
                s_slot[k] = np;
                lastb = ((k / H_DIM) * (B_DIM * H_DIM) + (k % H_DIM)) * S2;
                mi[8 + np] = lastb;
                ++np;
            } else s_slot[k] = -1;
        }
        for (int p = np; p < 160; ++p) mi[8 + p] = lastb;   // clamp pads
        mi[0] = np;
    }
    __syncthreads();
    if (t < 144) {
        const int sl = s_slot[t];
        if (sl >= 0) {
            const int l = t / H_DIM, h = t % H_DIM;
            int wd0 = 0, wd1 = 0, wd2 = 0, wd3 = 0, wd4 = 0, wd5 = 0, wd6 = 0, wd7 = 0;
#pragma unroll
            for (int m = 0; m < M_DIM; ++m) {
                const int w = (int)s_cl[m][l] * (int)s_ch[m][h];
                const int sh = (m & 3) * 8;
                switch (m >> 2) {
                    case 0: wd0 |= w << sh; break;
                    case 1: wd1 |= w << sh; break;
                    case 2: wd2 |= w << sh; break;
                    case 3: wd3 |= w << sh; break;
                    case 4: wd4 |= w << sh; break;
                    case 5: wd5 |= w << sh; break;
                    case 6: wd6 |= w << sh; break;
                    case 7: wd7 |= w << sh; break;
                }
            }
            int* wp = mi + 168 + sl * 8;
            wp[0] = wd0; wp[1] = wd1; wp[2] = wd2; wp[3] = wd3;
            wp[4] = wd4; wp[5] = wd5; wp[6] = wd6; wp[7] = wd7;
        }
    }
}

// ---------------- main: plane-pair streaming with counted-vmcnt pipeline ------
// 512 threads = 8 waves. Plane loop: thread = (b = wave, st2 = lane).
// Stage: wave w stages 1 KB of the 8 KB pair: plane-half w>>2, b-pair w&3.
__global__ __launch_bounds__(512, 1) void pfe_gather(
    const float* __restrict__ attn, const float* __restrict__ refs,
    const int* __restrict__ mi, float* __restrict__ part)
{
    __shared__ __align__(16) float smem[M_DIM * PMSTRIDE];  // 131328 B; first 64KB = stage pool
    __shared__ __align__(16) int s_pbase[160];
    __shared__ __align__(16) int s_ww[1176];

    const int t = threadIdx.x;
    const int lane = t & 63, w = t >> 6;
    for (int i = t; i < 160; i += 512) s_pbase[i] = mi[8 + i];
    for (int i = t; i < 1176; i += 512) s_ww[i] = mi[168 + i];
    const int np = mi[0];
    const int nsteps = (np + 1) >> 1;
    __syncthreads();

    const unsigned off0 = (unsigned)blockIdx.x * C;   // st offset of this chunk
    const unsigned sb   = (unsigned)((w & 3) * 2 + (lane >> 5));   // staged b
    const unsigned sst4 = (unsigned)(lane & 31) * 4u;              // staged st

    float2 acc[M_DIM];
#pragma unroll
    for (int m = 0; m < M_DIM; ++m) acc[m] = make_float2(0.f, 0.f);

    // prologue: issue DEPTH pair-stages (1 load-instr per wave per step)
#pragma unroll
    for (int s = 0; s < DEPTH; ++s) {
        const int pbw = s_pbase[2 * s + (w >> 2)];
        const float* src = attn + (unsigned)pbw + sb * (unsigned)HS2 + off0 + sst4;
        __builtin_amdgcn_global_load_lds((GAS*)src,
            (LAS*)(smem + s * 2048 + (w >> 2) * 1024 + (w & 3) * 256), 16, 0, 0);
    }

#define PROC_WORD(SW, Q, V)                                            \
    if (SW) {                                                          \
        const float f0 = (float)((SW) & 255);                          \
        const float f1 = (float)(((SW) >> 8) & 255);                   \
        const float f2 = (float)(((SW) >> 16) & 255);                  \
        const float f3 = (float)(((SW) >> 24) & 255);                  \
        acc[4*(Q)+0].x = fmaf(f0, (V).x, acc[4*(Q)+0].x);              \
        acc[4*(Q)+0].y = fmaf(f0, (V).y, acc[4*(Q)+0].y);              \
        acc[4*(Q)+1].x = fmaf(f1, (V).x, acc[4*(Q)+1].x);              \
        acc[4*(Q)+1].y = fmaf(f1, (V).y, acc[4*(Q)+1].y);              \
        acc[4*(Q)+2].x = fmaf(f2, (V).x, acc[4*(Q)+2].x);              \
        acc[4*(Q)+2].y = fmaf(f2, (V).y, acc[4*(Q)+2].y);              \
        acc[4*(Q)+3].x = fmaf(f3, (V).x, acc[4*(Q)+3].x);              \
        acc[4*(Q)+3].y = fmaf(f3, (V).y, acc[4*(Q)+3].y);              \
    }

    for (int s = 0; s < nsteps; ++s) {
        asm volatile("s_waitcnt vmcnt(5)" ::: "memory");   // pair s landed
        __builtin_amdgcn_s_barrier();
        __builtin_amdgcn_sched_barrier(0);

        // issue pair s+DEPTH into slot (s+DEPTH)%8 (clamped sources past np)
        {
            const int sp = s + DEPTH;
            const int pbw = s_pbase[2 * sp + (w >> 2)];
            const float* src = attn + (unsigned)pbw + sb * (unsigned)HS2 + off0 + sst4;
            __builtin_amdgcn_global_load_lds((GAS*)src,
                (LAS*)(smem + (sp & (NSLOT - 1)) * 2048 + (w >> 2) * 1024 + (w & 3) * 256),
                16, 0, 0);
        }

        const int slot = s & (NSLOT - 1);
        const float* bp = smem + slot * 2048 + w * 128 + lane * 2;
        const float2 v0 = *reinterpret_cast<const float2*>(bp);
        const float2 v1 = *reinterpret_cast<const float2*>(bp + 1024);

        const int p0 = 2 * s, p1 = 2 * s + 1;
        const int4 wa0 = *reinterpret_cast<const int4*>(s_ww + p0 * 8);
        const int4 wb0 = *reinterpret_cast<const int4*>(s_ww + p0 * 8 + 4);
        const int4 wa1 = *reinterpret_cast<const int4*>(s_ww + p1 * 8);
        const int4 wb1 = *reinterpret_cast<const int4*>(s_ww + p1 * 8 + 4);

        {
            const int s0 = __builtin_amdgcn_readfirstlane(wa0.x);
            const int s1 = __builtin_amdgcn_readfirstlane(wa0.y);
            const int s2 = __builtin_amdgcn_readfirstlane(wa0.z);
            const int s3 = __builtin_amdgcn_readfirstlane(wa0.w);
            const int s4 = __builtin_amdgcn_readfirstlane(wb0.x);
            const int s5 = __builtin_amdgcn_readfirstlane(wb0.y);
            const int s6 = __builtin_amdgcn_readfirstlane(wb0.z);
            const int s7 = __builtin_amdgcn_readfirstlane(wb0.w);
            PROC_WORD(s0, 0, v0) PROC_WORD(s1, 1, v0) PROC_WORD(s2, 2, v0) PROC_WORD(s3, 3, v0)
            PROC_WORD(s4, 4, v0) PROC_WORD(s5, 5, v0) PROC_WORD(s6, 6, v0) PROC_WORD(s7, 7, v0)
        }
        {
            const int s0 = __builtin_amdgcn_readfirstlane(wa1.x);
            const int s1 = __builtin_amdgcn_readfirstlane(wa1.y);
            const int s2 = __builtin_amdgcn_readfirstlane(wa1.z);
            const int s3 = __builtin_amdgcn_readfirstlane(wa1.w);
            const int s4 = __builtin_amdgcn_readfirstlane(wb1.x);
            const int s5 = __builtin_amdgcn_readfirstlane(wb1.y);
            const int s6 = __builtin_amdgcn_readfirstlane(wb1.z);
            const int s7 = __builtin_amdgcn_readfirstlane(wb1.w);
            PROC_WORD(s0, 0, v1) PROC_WORD(s1, 1, v1) PROC_WORD(s2, 2, v1) PROC_WORD(s3, 3, v1)
            PROC_WORD(s4, 4, v1) PROC_WORD(s5, 5, v1) PROC_WORD(s6, 6, v1) PROC_WORD(s7, 7, v1)
        }
    }
#undef PROC_WORD

    __builtin_amdgcn_sched_barrier(0);
    __syncthreads();   // full drain (incl. pad prefetches); stage pool now dead

    // ---- write pm (overlay smem): pm[m][b][st], m-stride PMSTRIDE ----
    const float c12 = 1.0f / 12.0f;
#pragma unroll
    for (int m = 0; m < M_DIM; ++m) {
        float2 p;
        p.x = acc[m].x * c12;
        p.y = acc[m].y * c12;
        *reinterpret_cast<float2*>(smem + m * PMSTRIDE + w * 128 + lane * 2) = p;
    }
    __syncthreads();

    // ---- stats: thread (m' = t>>4, r = t&15), 4 st-pairs, serial over b ----
    const int mp = t >> 4;
    const int r  = t & 15;
    float zacc0 = 0.f, zacc1 = 0.f, zacc2 = 0.f, zacc3 = 0.f;
    float zacc4 = 0.f, zacc5 = 0.f, zacc6 = 0.f, zacc7 = 0.f;
#pragma unroll
    for (int i = 0; i < 4; ++i) {
        const int st = r * 2 + 32 * i;
        float2 x[8];
#pragma unroll
        for (int b = 0; b < 8; ++b)
            x[b] = *reinterpret_cast<const float2*>(smem + mp * PMSTRIDE + b * 128 + st);
        float mx = 0.f, my = 0.f;
#pragma unroll
        for (int b = 0; b < 8; ++b) { mx += x[b].x; my += x[b].y; }
        mx *= 0.125f; my *= 0.125f;
        float sx = 0.f, sy = 0.f;
#pragma unroll
        for (int b = 0; b < 8; ++b) {
            const float dx = x[b].x - mx, dy = x[b].y - my;
            sx = fmaf(dx, dx, sx); sy = fmaf(dy, dy, sy);
        }
        const float invx = 1.0f / fmaxf(sqrtf(sx * (1.0f / 7.0f)), 1e-8f);
        const float invy = 1.0f / fmaxf(sqrtf(sy * (1.0f / 7.0f)), 1e-8f);
        const float2 rv = *reinterpret_cast<const float2*>(
            refs + (size_t)mp * S2 + off0 + (unsigned)st);
#pragma unroll
        for (int b = 0; b < 8; ++b) {
            const float zx = (x[b].x - rv.x) * invx;
            const float zy = (x[b].y - rv.y) * invy;
            const float zz = fmaf(zx, zx, zy * zy);
            switch (b) {
                case 0: zacc0 += zz; break;  case 1: zacc1 += zz; break;
                case 2: zacc2 += zz; break;  case 3: zacc3 += zz; break;
                case 4: zacc4 += zz; break;  case 5: zacc5 += zz; break;
                case 6: zacc6 += zz; break;  case 7: zacc7 += zz; break;
            }
        }
    }
    // reduce over r (lane bits 0..3)
#define RED(Z) { Z += __shfl_xor(Z, 1); Z += __shfl_xor(Z, 2); \
                 Z += __shfl_xor(Z, 4); Z += __shfl_xor(Z, 8); }
    RED(zacc0) RED(zacc1) RED(zacc2) RED(zacc3)
    RED(zacc4) RED(zacc5) RED(zacc6) RED(zacc7)
#undef RED
    if (r == 0) {
        float4 o0 = make_float4(zacc0, zacc1, zacc2, zacc3);
        float4 o1 = make_float4(zacc4, zacc5, zacc6, zacc7);
        float* pp = part + blockIdx.x * 256 + mp * 8;
        *reinterpret_cast<float4*>(pp)     = o0;
        *reinterpret_cast<float4*>(pp + 4) = o1;
    }
}

// ---------------- deterministic final reduction ----------------
__global__ __launch_bounds__(256) void pfe_final(
    const float* __restrict__ part, float* __restrict__ out)
{
    const int t = threadIdx.x;          // t = m*8 + b
    float s = 0.f;
    for (int blk = 0; blk < NCH; ++blk) s += part[blk * 256 + t];
    out[(t & 7) * M_DIM + (t >> 3)] = s * (1.0f / (float)S2);
}

// ---------------- fallback path (tiny ws): per-(m,chunk) atomic ----------------
__global__ void pfe_zero(float* __restrict__ out) {
    if (threadIdx.x < M_DIM * B_DIM) out[threadIdx.x] = 0.f;
}

#define FCH 512
#define FNCH (S2 / FCH)
__global__ __launch_bounds__(128) void pfe_fallback(
    const float* __restrict__ attn, const float* __restrict__ refs,
    const int* __restrict__ lidx, const int* __restrict__ hidx,
    float* __restrict__ out)
{
    const int p = blockIdx.x;
    const int m = p & (M_DIM - 1);
    const int chunk = p >> 5;
    const int tid = threadIdx.x;
    const unsigned st = (unsigned)chunk * FCH + (unsigned)tid * 4;

    __shared__ int   s_mk[NL * NH];
    __shared__ float s_mw[NL * NH];
    __shared__ int   s_nm;
    __shared__ float s_red[2 * B_DIM];

    if (tid == 0) {
        int keys[NL * NH];
        for (int i = 0; i < NL; ++i) {
            const int l = lidx[m * NL + i];
            for (int j = 0; j < NH; ++j) keys[i * NH + j] = l * 16 + hidx[m * NH + j];
        }
        for (int i = 1; i < NL * NH; ++i) {
            const int k = keys[i]; int j = i - 1;
            for (; j >= 0 && keys[j] > k; --j) keys[j + 1] = keys[j];
            keys[j + 1] = k;
        }
        int nm = 0;
        for (int i = 0; i < NL * NH; ++i) {
            if (nm > 0 && s_mk[nm - 1] == keys[i]) s_mw[nm - 1] += 1.0f;
            else { s_mk[nm] = keys[i]; s_mw[nm] = 1.0f; ++nm; }
        }
        s_nm = nm;
    }
    __syncthreads();

    const float4 r = *reinterpret_cast<const float4*>(refs + (unsigned)m * (unsigned)S2 + st);
    float4 acc[B_DIM];
    for (int bb = 0; bb < B_DIM; ++bb) acc[bb] = make_float4(0.f, 0.f, 0.f, 0.f);
    const int nm = s_nm;
    for (int e = 0; e < nm; ++e) {
        const int k = s_mk[e]; const float w = s_mw[e];
        const int l = k >> 4, h = k & 15;
        const unsigned base = (unsigned)(l * (B_DIM * H_DIM) + h) * (unsigned)S2 + st;
        for (int bb = 0; bb < B_DIM; ++bb) {
            const float4 v = *reinterpret_cast<const float4*>(
                attn + base + (unsigned)bb * (unsigned)HS2);
            acc[bb].x = fmaf(w, v.x, acc[bb].x); acc[bb].y = fmaf(w, v.y, acc[bb].y);
            acc[bb].z = fmaf(w, v.z, acc[bb].z); acc[bb].w = fmaf(w, v.w, acc[bb].w);
        }
    }
    const float c12 = 1.0f / 12.0f;
    float4 pmv[B_DIM];
    for (int bb = 0; bb < B_DIM; ++bb) {
        pmv[bb].x = acc[bb].x * c12; pmv[bb].y = acc[bb].y * c12;
        pmv[bb].z = acc[bb].z * c12; pmv[bb].w = acc[bb].w * c12;
    }
    float4 mu = make_float4(0.f, 0.f, 0.f, 0.f);
    for (int bb = 0; bb < B_DIM; ++bb) {
        mu.x += pmv[bb].x; mu.y += pmv[bb].y; mu.z += pmv[bb].z; mu.w += pmv[bb].w;
    }
    mu.x *= 0.125f; mu.y *= 0.125f; mu.z *= 0.125f; mu.w *= 0.125f;
    float4 ss = make_float4(0.f, 0.f, 0.f, 0.f);
    for (int bb = 0; bb < B_DIM; ++bb) {
        const float dx = pmv[bb].x - mu.x, dy = pmv[bb].y - mu.y,
                    dz = pmv[bb].z - mu.z, dw = pmv[bb].w - mu.w;
        ss.x += dx * dx; ss.y += dy * dy; ss.z += dz * dz; ss.w += dw * dw;
    }
    const float c7 = 1.0f / 7.0f;
    float4 inv;
    inv.x = 1.0f / fmaxf(sqrtf(ss.x * c7), 1e-8f);
    inv.y = 1.0f / fmaxf(sqrtf(ss.y * c7), 1e-8f);
    inv.z = 1.0f / fmaxf(sqrtf(ss.z * c7), 1e-8f);
    inv.w = 1.0f / fmaxf(sqrtf(ss.w * c7), 1e-8f);
    float s[B_DIM];
    for (int bb = 0; bb < B_DIM; ++bb) {
        const float zx = (pmv[bb].x - r.x) * inv.x;
        const float zy = (pmv[bb].y - r.y) * inv.y;
        const float zz = (pmv[bb].z - r.z) * inv.z;
        const float zw = (pmv[bb].w - r.w) * inv.w;
        s[bb] = zx * zx + zy * zy + zz * zz + zw * zw;
    }
    for (int bb = 0; bb < B_DIM; ++bb) {
        float v = s[bb];
        for (int off = 32; off > 0; off >>= 1) v += __shfl_down(v, off);
        s[bb] = v;
    }
    const int lane = tid & 63, wave = tid >> 6;
    if (lane == 0) for (int bb = 0; bb < B_DIM; ++bb) s_red[wave * B_DIM + bb] = s[bb];
    __syncthreads();
    if (tid < B_DIM) {
        const float tot = (s_red[tid] + s_red[B_DIM + tid]) * (1.0f / (float)S2);
        atomicAdd(&out[tid * M_DIM + m], tot);
    }
}

extern "C" void kernel_launch(void* const* d_in, const int* in_sizes, int n_in,
                              void* d_out, int out_size, void* d_ws, size_t ws_size,
                              hipStream_t stream) {
    const float* attn = (const float*)d_in[0];
    const float* refs = (const float*)d_in[1];
    const int*   lidx = (const int*)d_in[2];
    const int*   hidx = (const int*)d_in[3];
    float* out = (float*)d_out;

    const size_t ws_needed = (size_t)(PART_FLOATS + META_INTS) * sizeof(float);

    if (ws_size >= ws_needed) {
        float* part = (float*)d_ws;
        int*   mi   = (int*)(part + PART_FLOATS);
        pfe_setup<<<1, 256, 0, stream>>>(lidx, hidx, mi);
        pfe_gather<<<NCH, 512, 0, stream>>>(attn, refs, mi, part);
        pfe_final<<<1, 256, 0, stream>>>(part, out);
    } else {
        pfe_zero<<<1, 256, 0, stream>>>(out);
        pfe_fallback<<<FNCH * M_DIM, 128, 0, stream>>>(attn, refs, lidx, hidx, out);
    }
}

// Round 7
// 164.303 us; speedup vs baseline: 2.2995x; 2.2995x over previous
//
#include <hip/hip_runtime.h>

// Problem constants (from reference setup_inputs)
#define L_DIM 12
#define B_DIM 8
#define H_DIM 12
#define S2    147456              // 384*384
#define M_DIM 32
#define NL 3
#define NH 4
#define HS2   (H_DIM * S2)        // batch stride in attn elements

// design: global->register plane streaming, no LDS staging, no barriers
#define C      128                // st elements per block (chunk)
#define NCH    (S2 / C)           // 1152 blocks
#define RED1   32                 // chunks per red1 block
#define NRED1  (NCH / RED1)       // 36

#define PART_FLOATS (NCH * 256)
#define MID_FLOATS  (NRED1 * 256)
#define META_INTS   2048
// mi layout: [0]=np ; [8..168) plane base elem offsets (padded/clamped) ;
//            [168..168+1176) weight bytes packed 4 m/int, 8 ints/plane (zero padded)

// ---------------- setup: parallel, LDS-only ----------------
__global__ __launch_bounds__(256) void pfe_setup(
    const int* __restrict__ lidx, const int* __restrict__ hidx, int* __restrict__ mi)
{
    __shared__ unsigned char s_cl[M_DIM][16];
    __shared__ unsigned char s_ch[M_DIM][16];
    __shared__ int s_used[144];
    __shared__ int s_slot[144];
    const int t = threadIdx.x;
    for (int i = t; i < 1176; i += 256) mi[168 + i] = 0;   // zero weight region
    if (t < M_DIM) {
        for (int l = 0; l < L_DIM; ++l) s_cl[t][l] = 0;
        for (int h = 0; h < H_DIM; ++h) s_ch[t][h] = 0;
        for (int i = 0; i < NL; ++i) s_cl[t][lidx[t * NL + i]]++;
        for (int j = 0; j < NH; ++j) s_ch[t][hidx[t * NH + j]]++;
    }
    __syncthreads();
    if (t < 144) {
        const int l = t / H_DIM, h = t % H_DIM;
        int u = 0;
        for (int m = 0; m < M_DIM; ++m) u |= (s_cl[m][l] && s_ch[m][h]) ? 1 : 0;
        s_used[t] = u;
    }
    __syncthreads();
    if (t == 0) {
        int np = 0, lastb = 0;
        for (int k = 0; k < 144; ++k) {
            if (s_used[k]) {
                s_slot[k] = np;
                lastb = ((k / H_DIM) * (B_DIM * H_DIM) + (k % H_DIM)) * S2;
                mi[8 + np] = lastb;
                ++np;
            } else s_slot[k] = -1;
        }
        for (int p = np; p < 160; ++p) mi[8 + p] = lastb;   // clamp pads (safe loads)
        mi[0] = np;
    }
    __syncthreads();
    if (t < 144) {
        const int sl = s_slot[t];
        if (sl >= 0) {
            const int l = t / H_DIM, h = t % H_DIM;
            int wd[8] = {0, 0, 0, 0, 0, 0, 0, 0};
#pragma unroll
            for (int g = 0; g < 8; ++g) {
                int w = 0;
#pragma unroll
                for (int j = 0; j < 4; ++j) {
                    const int m = g * 4 + j;
                    w |= ((int)s_cl[m][l] * (int)s_ch[m][h]) << (8 * j);
                }
                wd[g] = w;
            }
            int* wp = mi + 168 + sl * 8;
#pragma unroll
            for (int g = 0; g < 8; ++g) wp[g] = wd[g];
        }
    }
}

// ---------------- main: global->register streaming, register scatter ----------
// 256 threads = 4 waves. thread = (b = t>>5, q = t&31) owns float4 at st=q*4.
// acc[32] float4 in VGPRs (statically indexed). No barriers in main loop.
__global__ __launch_bounds__(256) void pfe_gather(
    const float* __restrict__ attn, const float* __restrict__ refs,
    const int* __restrict__ mi, float* __restrict__ part)
{
    __shared__ int s_pbase[160];
    __shared__ int s_ww[1176];
    __shared__ float s_x[8 * B_DIM * C];   // 32 KB exchange (8 m-slice)

    const int t = threadIdx.x;
    for (int i = t; i < 160; i += 256) s_pbase[i] = mi[8 + i];
    for (int i = t; i < 1176; i += 256) s_ww[i] = mi[168 + i];
    const int np4 = (mi[0] + 3) & ~3;
    __syncthreads();

    const int b = t >> 5, q = t & 31;
    const unsigned off0 = (unsigned)blockIdx.x * C;
    const unsigned fixoff = (unsigned)b * (unsigned)HS2 + off0 + (unsigned)q * 4u;

    float4 acc[M_DIM];
#pragma unroll
    for (int m = 0; m < M_DIM; ++m) acc[m] = make_float4(0.f, 0.f, 0.f, 0.f);

#define LD(P) (*reinterpret_cast<const float4*>(attn + (unsigned)s_pbase[P] + fixoff))

#define PROC_WORD(SW, G, V)                                             \
    if (SW) {                                                           \
        const float f0 = (float)((SW) & 255);                           \
        const float f1 = (float)(((SW) >> 8) & 255);                    \
        const float f2 = (float)(((SW) >> 16) & 255);                   \
        const float f3 = (float)(((SW) >> 24) & 255);                   \
        acc[4*(G)+0].x = fmaf(f0, (V).x, acc[4*(G)+0].x);               \
        acc[4*(G)+0].y = fmaf(f0, (V).y, acc[4*(G)+0].y);               \
        acc[4*(G)+0].z = fmaf(f0, (V).z, acc[4*(G)+0].z);               \
        acc[4*(G)+0].w = fmaf(f0, (V).w, acc[4*(G)+0].w);               \
        acc[4*(G)+1].x = fmaf(f1, (V).x, acc[4*(G)+1].x);               \
        acc[4*(G)+1].y = fmaf(f1, (V).y, acc[4*(G)+1].y);               \
        acc[4*(G)+1].z = fmaf(f1, (V).z, acc[4*(G)+1].z);               \
        acc[4*(G)+1].w = fmaf(f1, (V).w, acc[4*(G)+1].w);               \
        acc[4*(G)+2].x = fmaf(f2, (V).x, acc[4*(G)+2].x);               \
        acc[4*(G)+2].y = fmaf(f2, (V).y, acc[4*(G)+2].y);               \
        acc[4*(G)+2].z = fmaf(f2, (V).z, acc[4*(G)+2].z);               \
        acc[4*(G)+2].w = fmaf(f2, (V).w, acc[4*(G)+2].w);               \
        acc[4*(G)+3].x = fmaf(f3, (V).x, acc[4*(G)+3].x);               \
        acc[4*(G)+3].y = fmaf(f3, (V).y, acc[4*(G)+3].y);               \
        acc[4*(G)+3].z = fmaf(f3, (V).z, acc[4*(G)+3].z);               \
        acc[4*(G)+3].w = fmaf(f3, (V).w, acc[4*(G)+3].w);               \
    }

#define PROC_PLANE(P, V)                                                \
    {                                                                   \
        const int4 wa = *reinterpret_cast<const int4*>(s_ww + (P) * 8); \
        const int4 wb = *reinterpret_cast<const int4*>(s_ww + (P) * 8 + 4); \
        const int w0 = __builtin_amdgcn_readfirstlane(wa.x);            \
        const int w1 = __builtin_amdgcn_readfirstlane(wa.y);            \
        const int w2 = __builtin_amdgcn_readfirstlane(wa.z);            \
        const int w3 = __builtin_amdgcn_readfirstlane(wa.w);            \
        const int w4 = __builtin_amdgcn_readfirstlane(wb.x);            \
        const int w5 = __builtin_amdgcn_readfirstlane(wb.y);            \
        const int w6 = __builtin_amdgcn_readfirstlane(wb.z);            \
        const int w7 = __builtin_amdgcn_readfirstlane(wb.w);            \
        PROC_WORD(w0, 0, V) PROC_WORD(w1, 1, V)                         \
        PROC_WORD(w2, 2, V) PROC_WORD(w3, 3, V)                         \
        PROC_WORD(w4, 4, V) PROC_WORD(w5, 5, V)                         \
        PROC_WORD(w6, 6, V) PROC_WORD(w7, 7, V)                         \
    }

    // 4-deep register prefetch pipeline (bases clamped past np -> safe loads)
    float4 n0 = LD(0), n1 = LD(1), n2 = LD(2), n3 = LD(3);
    for (int p = 0; p < np4; p += 4) {
        const float4 c0 = n0, c1 = n1, c2 = n2, c3 = n3;
        n0 = LD(p + 4); n1 = LD(p + 5); n2 = LD(p + 6); n3 = LD(p + 7);
        PROC_PLANE(p + 0, c0)
        PROC_PLANE(p + 1, c1)
        PROC_PLANE(p + 2, c2)
        PROC_PLANE(p + 3, c3)
    }
#undef PROC_PLANE
#undef PROC_WORD
#undef LD

    const float c12 = 1.0f / 12.0f;
    const int mm = t >> 5;   // 0..7 within slice (half-wave uniform)

    // ---- stats: 4 slices of 8 m's through 32 KB LDS exchange ----
    for (int sl = 0; sl < 4; ++sl) {
        __syncthreads();   // previous slice's reads done
#pragma unroll
        for (int k = 0; k < 8; ++k) {
            const float4 a = acc[sl * 8 + k];
            float4 p;
            p.x = a.x * c12; p.y = a.y * c12; p.z = a.z * c12; p.w = a.w * c12;
            *reinterpret_cast<float4*>(&s_x[(k * B_DIM + b) * C + q * 4]) = p;
        }
        __syncthreads();   // slice data ready

        const int m = sl * 8 + mm;
        float4 x[B_DIM];
#pragma unroll
        for (int bb = 0; bb < B_DIM; ++bb)
            x[bb] = *reinterpret_cast<const float4*>(&s_x[(mm * B_DIM + bb) * C + q * 4]);
        float4 mu = make_float4(0.f, 0.f, 0.f, 0.f);
#pragma unroll
        for (int bb = 0; bb < B_DIM; ++bb) {
            mu.x += x[bb].x; mu.y += x[bb].y; mu.z += x[bb].z; mu.w += x[bb].w;
        }
        mu.x *= 0.125f; mu.y *= 0.125f; mu.z *= 0.125f; mu.w *= 0.125f;
        float4 ss = make_float4(0.f, 0.f, 0.f, 0.f);
#pragma unroll
        for (int bb = 0; bb < B_DIM; ++bb) {
            const float dx = x[bb].x - mu.x, dy = x[bb].y - mu.y,
                        dz = x[bb].z - mu.z, dw = x[bb].w - mu.w;
            ss.x = fmaf(dx, dx, ss.x); ss.y = fmaf(dy, dy, ss.y);
            ss.z = fmaf(dz, dz, ss.z); ss.w = fmaf(dw, dw, ss.w);
        }
        const float c7 = 1.0f / 7.0f;
        float4 inv;
        inv.x = 1.0f / fmaxf(sqrtf(ss.x * c7), 1e-8f);
        inv.y = 1.0f / fmaxf(sqrtf(ss.y * c7), 1e-8f);
        inv.z = 1.0f / fmaxf(sqrtf(ss.z * c7), 1e-8f);
        inv.w = 1.0f / fmaxf(sqrtf(ss.w * c7), 1e-8f);
        const float4 rv = *reinterpret_cast<const float4*>(
            refs + (size_t)m * S2 + off0 + (unsigned)q * 4u);

        float zs[B_DIM];
#pragma unroll
        for (int bb = 0; bb < B_DIM; ++bb) {
            const float zx = (x[bb].x - rv.x) * inv.x;
            const float zy = (x[bb].y - rv.y) * inv.y;
            const float zz = (x[bb].z - rv.z) * inv.z;
            const float zw = (x[bb].w - rv.w) * inv.w;
            zs[bb] = fmaf(zx, zx, fmaf(zy, zy, fmaf(zz, zz, zw * zw)));
        }
        // reduce over q (lane bits 0..4, stays within 32-lane half-wave)
#pragma unroll
        for (int bb = 0; bb < B_DIM; ++bb) {
            float v = zs[bb];
            v += __shfl_xor(v, 1);
            v += __shfl_xor(v, 2);
            v += __shfl_xor(v, 4);
            v += __shfl_xor(v, 8);
            v += __shfl_xor(v, 16);
            zs[bb] = v;
        }
        if (q == 0) {
            float* pp = part + blockIdx.x * 256 + m * B_DIM;
            *reinterpret_cast<float4*>(pp) =
                make_float4(zs[0], zs[1], zs[2], zs[3]);
            *reinterpret_cast<float4*>(pp + 4) =
                make_float4(zs[4], zs[5], zs[6], zs[7]);
        }
    }
}

// ---------------- deterministic two-stage reduction ----------------
__global__ __launch_bounds__(256) void pfe_red1(
    const float* __restrict__ part, float* __restrict__ mid)
{
    const int t = threadIdx.x;
    const int c0 = blockIdx.x * RED1;
    float s = 0.f;
#pragma unroll
    for (int i = 0; i < RED1; ++i) s += part[(c0 + i) * 256 + t];
    mid[blockIdx.x * 256 + t] = s;
}

__global__ __launch_bounds__(256) void pfe_red2(
    const float* __restrict__ mid, float* __restrict__ out)
{
    const int t = threadIdx.x;          // t = m*8 + b
    float s = 0.f;
#pragma unroll
    for (int i = 0; i < NRED1; ++i) s += mid[i * 256 + t];
    out[(t & 7) * M_DIM + (t >> 3)] = s * (1.0f / (float)S2);
}

// ---------------- fallback path (tiny ws): per-(m,chunk) atomic ----------------
__global__ void pfe_zero(float* __restrict__ out) {
    if (threadIdx.x < M_DIM * B_DIM) out[threadIdx.x] = 0.f;
}

#define FCH 512
#define FNCH (S2 / FCH)
__global__ __launch_bounds__(128) void pfe_fallback(
    const float* __restrict__ attn, const float* __restrict__ refs,
    const int* __restrict__ lidx, const int* __restrict__ hidx,
    float* __restrict__ out)
{
    const int p = blockIdx.x;
    const int m = p & (M_DIM - 1);
    const int chunk = p >> 5;
    const int tid = threadIdx.x;
    const unsigned st = (unsigned)chunk * FCH + (unsigned)tid * 4;

    __shared__ int   s_mk[NL * NH];
    __shared__ float s_mw[NL * NH];
    __shared__ int   s_nm;
    __shared__ float s_red[2 * B_DIM];

    if (tid == 0) {
        int keys[NL * NH];
        for (int i = 0; i < NL; ++i) {
            const int l = lidx[m * NL + i];
            for (int j = 0; j < NH; ++j) keys[i * NH + j] = l * 16 + hidx[m * NH + j];
        }
        for (int i = 1; i < NL * NH; ++i) {
            const int k = keys[i]; int j = i - 1;
            for (; j >= 0 && keys[j] > k; --j) keys[j + 1] = keys[j];
            keys[j + 1] = k;
        }
        int nm = 0;
        for (int i = 0; i < NL * NH; ++i) {
            if (nm > 0 && s_mk[nm - 1] == keys[i]) s_mw[nm - 1] += 1.0f;
            else { s_mk[nm] = keys[i]; s_mw[nm] = 1.0f; ++nm; }
        }
        s_nm = nm;
    }
    __syncthreads();

    const float4 r = *reinterpret_cast<const float4*>(refs + (unsigned)m * (unsigned)S2 + st);
    float4 acc[B_DIM];
    for (int bb = 0; bb < B_DIM; ++bb) acc[bb] = make_float4(0.f, 0.f, 0.f, 0.f);
    const int nm = s_nm;
    for (int e = 0; e < nm; ++e) {
        const int k = s_mk[e]; const float w = s_mw[e];
        const int l = k >> 4, h = k & 15;
        const unsigned base = (unsigned)(l * (B_DIM * H_DIM) + h) * (unsigned)S2 + st;
        for (int bb = 0; bb < B_DIM; ++bb) {
            const float4 v = *reinterpret_cast<const float4*>(
                attn + base + (unsigned)bb * (unsigned)HS2);
            acc[bb].x = fmaf(w, v.x, acc[bb].x); acc[bb].y = fmaf(w, v.y, acc[bb].y);
            acc[bb].z = fmaf(w, v.z, acc[bb].z); acc[bb].w = fmaf(w, v.w, acc[bb].w);
        }
    }
    const float c12 = 1.0f / 12.0f;
    float4 pmv[B_DIM];
    for (int bb = 0; bb < B_DIM; ++bb) {
        pmv[bb].x = acc[bb].x * c12; pmv[bb].y = acc[bb].y * c12;
        pmv[bb].z = acc[bb].z * c12; pmv[bb].w = acc[bb].w * c12;
    }
    float4 mu = make_float4(0.f, 0.f, 0.f, 0.f);
    for (int bb = 0; bb < B_DIM; ++bb) {
        mu.x += pmv[bb].x; mu.y += pmv[bb].y; mu.z += pmv[bb].z; mu.w += pmv[bb].w;
    }
    mu.x *= 0.125f; mu.y *= 0.125f; mu.z *= 0.125f; mu.w *= 0.125f;
    float4 ss = make_float4(0.f, 0.f, 0.f, 0.f);
    for (int bb = 0; bb < B_DIM; ++bb) {
        const float dx = pmv[bb].x - mu.x, dy = pmv[bb].y - mu.y,
                    dz = pmv[bb].z - mu.z, dw = pmv[bb].w - mu.w;
        ss.x += dx * dx; ss.y += dy * dy; ss.z += dz * dz; ss.w += dw * dw;
    }
    const float c7 = 1.0f / 7.0f;
    float4 inv;
    inv.x = 1.0f / fmaxf(sqrtf(ss.x * c7), 1e-8f);
    inv.y = 1.0f / fmaxf(sqrtf(ss.y * c7), 1e-8f);
    inv.z = 1.0f / fmaxf(sqrtf(ss.z * c7), 1e-8f);
    inv.w = 1.0f / fmaxf(sqrtf(ss.w * c7), 1e-8f);
    float s[B_DIM];
    for (int bb = 0; bb < B_DIM; ++bb) {
        const float zx = (pmv[bb].x - r.x) * inv.x;
        const float zy = (pmv[bb].y - r.y) * inv.y;
        const float zz = (pmv[bb].z - r.z) * inv.z;
        const float zw = (pmv[bb].w - r.w) * inv.w;
        s[bb] = zx * zx + zy * zy + zz * zz + zw * zw;
    }
    for (int bb = 0; bb < B_DIM; ++bb) {
        float v = s[bb];
        for (int off = 32; off > 0; off >>= 1) v += __shfl_down(v, off);
        s[bb] = v;
    }
    const int lane = tid & 63, wave = tid >> 6;
    if (lane == 0) for (int bb = 0; bb < B_DIM; ++bb) s_red[wave * B_DIM + bb] = s[bb];
    __syncthreads();
    if (tid < B_DIM) {
        const float tot = (s_red[tid] + s_red[B_DIM + tid]) * (1.0f / (float)S2);
        atomicAdd(&out[tid * M_DIM + m], tot);
    }
}

extern "C" void kernel_launch(void* const* d_in, const int* in_sizes, int n_in,
                              void* d_out, int out_size, void* d_ws, size_t ws_size,
                              hipStream_t stream) {
    const float* attn = (const float*)d_in[0];
    const float* refs = (const float*)d_in[1];
    const int*   lidx = (const int*)d_in[2];
    const int*   hidx = (const int*)d_in[3];
    float* out = (float*)d_out;

    const size_t ws_needed =
        (size_t)(PART_FLOATS + MID_FLOATS + META_INTS) * sizeof(float);

    if (ws_size >= ws_needed) {
        float* part = (float*)d_ws;
        float* mid  = part + PART_FLOATS;
        int*   mi   = (int*)(mid + MID_FLOATS);
        pfe_setup<<<1, 256, 0, stream>>>(lidx, hidx, mi);
        pfe_gather<<<NCH, 256, 0, stream>>>(attn, refs, mi, part);
        pfe_red1<<<NRED1, 256, 0, stream>>>(part, mid);
        pfe_red2<<<1, 256, 0, stream>>>(mid, out);
    } else {
        pfe_zero<<<1, 256, 0, stream>>>(out);
        pfe_fallback<<<FNCH * M_DIM, 128, 0, stream>>>(attn, refs, lidx, hidx, out);
    }
}